// Round 7
// baseline (261.913 us; speedup 1.0000x reference)
//
#include <hip/hip_runtime.h>
#include <math.h>

// Problem constants
#define C 256
#define K 1024
#define SS 4096          // 16*16*16 spatial
#define NB 8             // batch
#define NN 32768         // NB*SS rows
#define ZQ_ELEMS 8388608 // NB*C*SS
#define OUT_LOSS 8388608
#define OUT_PERP 8388609
#define OUT_IDX  8388610
#define OUT_MD   8421378

// workspace float layout
#define WS_SZ2   0       // sum z^2 (scalar)
#define WS_SE2   1       // sum e^2 (scalar)
#define WS_LOSS  2       // sum (zq-z)^2 (scalar)
#define WS_ZSUM  8       // [256] column sums of zf
#define WS_ESUM  264     // [256] column sums of emb
#define WS_CNT   520     // [1024] histogram (float)
#define WS_E2R   1544    // [1024] ||e_k||^2, numpy-pairwise f32
#define WS_Z2N   2568    // [32768] ||z_n||^2, numpy-pairwise f32
#define WS_FLG   35336   // int region: [0]=list cnt, [1]=ov cnt, [2..2+NN) entries
#define WS_EH    68608   // [1024*256] u16 emb-hi
#define WS_CAND  330752  // [NN*4] u16 candidate code indices per queue slot

// Candidate machinery: the reference computes d = fl(fl(z2+e2) - fl(2g)).
// Single-pass bf16 MFMA: per-element err rms ~9e-7 -> dot sigma ~1.4e-5 ->
// d-shift sigma ~2.9e-5. Argmin containment needs keep >= 2*s_max; s_max
// over 3.4e7 dots ~5.4 sigma -> keep >= 10.8 sigma. keep = 14 sigma
// (TF 1.6e-6 rel ~ 4.1e-4 at d~256), collect = 16 sigma (TC 1.8e-6).
// Exact-f64 fixup arbitrates all near-ties; OV rows get a block-parallel
// full scan. (R5/R6 passed with these exact windows/queues.)
#define TC_FACT 1.8e-6f
#define TF_FACT 1.6e-6f
#define CAP 4            // max candidates per flagged row in global queue
#define CAP_BIG 24       // LDS collection capacity per row
#define OV 7             // sentinel: row went to the OV queue

typedef __attribute__((ext_vector_type(8))) short short8;
typedef __attribute__((ext_vector_type(4))) float f32x4;
typedef unsigned short u16;

__device__ inline u16 f2bf(float x) {  // f32 -> bf16 RNE
  unsigned u = __float_as_uint(x);
  unsigned r = (u + 0x7fffu + ((u >> 16) & 1u)) >> 16;
  return (u16)r;
}
__device__ inline float bf2f(u16 h) { return __uint_as_float(((unsigned)h) << 16); }

// async global->LDS 16B: LDS dest is wave-uniform base + lane*16 (linear);
// swizzle is applied on the per-lane GLOBAL address instead (m173 pattern).
__device__ __forceinline__ void gl_lds16(const u16* g, u16* l) {
  __builtin_amdgcn_global_load_lds(
      (const __attribute__((address_space(1))) unsigned int*)g,
      (__attribute__((address_space(3))) unsigned int*)l,
      16, 0, 0);
}

// ---- numpy pairwise f32 sum of squares, 256 contiguous elements ----
__device__ inline float np_sumsq_256(const float* __restrict__ a) {
  float tot = 0.f;
  #pragma unroll
  for (int h = 0; h < 2; ++h) {
    const float* p = a + 128 * h;
    float r[8];
    #pragma unroll
    for (int j = 0; j < 8; ++j) r[j] = __fmul_rn(p[j], p[j]);
    for (int i = 8; i < 128; i += 8) {
      #pragma unroll
      for (int j = 0; j < 8; ++j) {
        float v = p[i + j];
        r[j] = __fadd_rn(r[j], __fmul_rn(v, v));
      }
    }
    float s01 = __fadd_rn(r[0], r[1]);
    float s23 = __fadd_rn(r[2], r[3]);
    float s45 = __fadd_rn(r[4], r[5]);
    float s67 = __fadd_rn(r[6], r[7]);
    float res = __fadd_rn(__fadd_rn(s01, s23), __fadd_rn(s45, s67));
    tot = (h == 0) ? res : __fadd_rn(tot, res);
  }
  return tot;
}

// ---------- emb prep: bf16 eh, e2[k], col sums, Se2 ----------
__global__ __launch_bounds__(256)
void emb_prep_k(const float* __restrict__ emb, float* __restrict__ ws,
                u16* __restrict__ eh) {
  int r0 = blockIdx.x * 16;   // 64 blocks x 16 rows
  int t = threadIdx.x;
  float s = 0.f;
  #pragma unroll
  for (int i = 0; i < 16; ++i) {
    size_t idx = (size_t)(r0 + i) * C + t;
    float v = emb[idx];
    s += v;
    eh[idx] = f2bf(v);
  }
  atomicAdd(&ws[WS_ESUM + t], s);
  if (t < 16) {
    float e2 = np_sumsq_256(emb + (size_t)(r0 + t) * C);
    ws[WS_E2R + r0 + t] = e2;
    atomicAdd(&ws[WS_SE2], e2);
  }
}

#define MROWS 64
#define ZS_STRIDE 260

// ---------- one pass over z: zsum[c], Sz2, z2np[n], bf16 zh ----------
__global__ __launch_bounds__(256)
void prep_z_k(const float* __restrict__ z, float* __restrict__ ws,
              u16* __restrict__ zh_g) {
  __shared__ float zs[MROWS * ZS_STRIDE];
  const int t = threadIdx.x;
  const int n0 = blockIdx.x * MROWS;
  const int b = n0 / SS;
  const int s0 = n0 % SS;
  {
    const int sl = t & 63, cg = t >> 6;
    const float* zb = z + (size_t)b * C * SS + s0 + sl;
    #pragma unroll
    for (int i = 0; i < 16; ++i) {
      int c = (cg * 16 + i) * 4;
      float4 v;
      v.x = zb[(size_t)(c + 0) * SS];
      v.y = zb[(size_t)(c + 1) * SS];
      v.z = zb[(size_t)(c + 2) * SS];
      v.w = zb[(size_t)(c + 3) * SS];
      *(float4*)&zs[sl * ZS_STRIDE + c] = v;
    }
  }
  __syncthreads();
  // column sums
  {
    float s = 0.f;
    #pragma unroll 8
    for (int r = 0; r < MROWS; ++r) s += zs[r * ZS_STRIDE + t];
    atomicAdd(&ws[WS_ZSUM + t], s);
  }
  // bf16, lane-linear coalesced short8 stores
  {
    #pragma unroll
    for (int i = 0; i < 8; ++i) {
      int q = i * 256 + t;          // short8 chunk 0..2047
      int row = q >> 5;             // 0..63
      int c0 = (q & 31) * 8;
      float4 va = *(const float4*)&zs[row * ZS_STRIDE + c0];
      float4 vb = *(const float4*)&zs[row * ZS_STRIDE + c0 + 4];
      float f[8] = {va.x, va.y, va.z, va.w, vb.x, vb.y, vb.z, vb.w};
      short8 hv;
      #pragma unroll
      for (int j = 0; j < 8; ++j) hv[j] = (short)f2bf(f[j]);
      *(short8*)&zh_g[(size_t)(n0 + row) * C + c0] = hv;
    }
  }
  // z2 (numpy-pairwise) + Sz2
  if (t < MROWS) {
    float z2 = np_sumsq_256(&zs[t * ZS_STRIDE]);
    ws[WS_Z2N + n0 + t] = z2;
    #pragma unroll
    for (int off = 32; off; off >>= 1) z2 += __shfl_down(z2, off);
    if (t == 0) atomicAdd(&ws[WS_SZ2], z2);
  }
}

// ---------- main: single-pass bf16 MFMA, 8-wave blocks, depth-3 pipeline ----------
// R7: R6's counters (MfmaUtil 9%, VALUBusy 18%, Occ 19.7%, all pipe floors
// ~8x under dur) say latency-bound at 8 waves/CU. Blocks go 256->512 threads
// (8 waves, 2x4 wave grid: wm=wid>>2 rows, wn=wid&3 cols) -> 16 waves/CU at
// the same 2 blocks/CU. Per wave: 32 rows x 32 cols, 8 MFMA/chunk, A-frags
// in regs (64 VGPR). B staged by global_load_lds into 4 buffers, prefetch
// depth 3: wait own vmcnt (stage(it) landed) BEFORE barrier (publishes all
// waves' stage(it)); stage(it+3) issued AFTER barrier into the buffer all
// waves finished at it-1. ~78 KB LDS, 2 blocks/CU, VGPR capped 128.
#define BM 64
#define BN 128
#define CH 64

__global__ __launch_bounds__(512, 4)
void vq_mfma_k(const u16* __restrict__ zh_g, const u16* __restrict__ eh_g,
               const float* __restrict__ e2row, const float* __restrict__ z2np,
               float* __restrict__ out_idx,
               int* __restrict__ qarr, u16* __restrict__ cand) {
  extern __shared__ u16 smem_u16[];
  u16* Bh4 = smem_u16;                         // [4][128][64] u16, swizzled
  float* e2all = (float*)(Bh4 + 4 * BN * CH);  // [1024]
  float* z2s  = e2all + K;                     // [64]
  float* lval = z2s + BM;                      // [64][CAP_BIG] candidate dq
  unsigned* Mlds = (unsigned*)(lval + BM * CAP_BIG);  // [64] running row min
  unsigned* cntl = Mlds + BM;                  // [64] append counters
  u16* lidx = (u16*)(cntl + BM);               // [64][CAP_BIG] candidate idx

  const int t = threadIdx.x;
  const int lane = t & 63;
  const int wid = t >> 6;          // 0..7
  const int wm = wid >> 2;         // 0..1 : row half
  const int wn = wid & 3;          // 0..3 : col quarter
  const int quad = lane >> 4, lr = lane & 15;
  const int row0 = blockIdx.x * BM;
  // per-lane pre-swizzled source offset within an 8-row group
  const int wrow = lane >> 3;
  const int pl = wrow * C + ((lane & 7) ^ wrow) * 8;

  // ---- prologue: LDS scalars, A->regs, first three B stages ----
  #pragma unroll
  for (int i = 0; i < 2; ++i) e2all[i * 512 + t] = e2row[i * 512 + t];
  if (t < BM) {
    z2s[t] = z2np[row0 + t];
    Mlds[t] = 0x7F800000u;  // +inf (positive floats order as uints)
    cntl[t] = 0u;
  }
  short8 areg[4][2][2];   // [ch][s][mi] : 64 VGPR, this wave's 32 rows
  #pragma unroll
  for (int ch = 0; ch < 4; ++ch)
    #pragma unroll
    for (int s = 0; s < 2; ++s)
      #pragma unroll
      for (int mi = 0; mi < 2; ++mi)
        areg[ch][s][mi] = *(const short8*)
          &zh_g[(size_t)(row0 + wm * 32 + mi * 16 + lr) * C + ch * CH + (s * 4 + quad) * 8];

  auto stageB = [&](int j) {   // stage chunk j -> buffer j&3 (2 loads/wave)
    u16* Bb = Bh4 + (j & 3) * (BN * CH);
    const u16* srcb = eh_g + (size_t)(j >> 2) * (BN * C) + (j & 3) * CH;
    #pragma unroll
    for (int i = 0; i < 2; ++i) {
      int grow = (wid * 2 + i) * 8;
      gl_lds16(&srcb[(size_t)grow * C + pl], &Bb[grow * CH]);
    }
  };
  stageB(0);
  stageB(1);
  stageB(2);

  float v1[8], i1f[8];
  #pragma unroll
  for (int s = 0; s < 8; ++s) { v1[s] = 3.4e38f; i1f[s] = 0.f; }
  f32x4 acc[2][2];
  #pragma unroll
  for (int mi = 0; mi < 2; ++mi)
    #pragma unroll
    for (int ni = 0; ni < 2; ++ni) acc[mi][ni] = (f32x4){0.f, 0.f, 0.f, 0.f};

  for (int nt = 0; nt < 8; ++nt) {
    #pragma unroll
    for (int ch = 0; ch < 4; ++ch) {
      const int it = nt * 4 + ch;
      // wait: own stage(it) landed (outstanding {it..it+2} = 6 -> vmcnt(4));
      // lgkmcnt(0) publishes LDS init/scoring writes at the barrier.
      if (ch < 2) {
        asm volatile("s_waitcnt vmcnt(4) lgkmcnt(0)" ::: "memory");
      } else if (ch == 2) {
        if (nt < 7) asm volatile("s_waitcnt vmcnt(4) lgkmcnt(0)" ::: "memory");
        else        asm volatile("s_waitcnt vmcnt(2) lgkmcnt(0)" ::: "memory");
      } else {
        if (nt < 7) asm volatile("s_waitcnt vmcnt(4) lgkmcnt(0)" ::: "memory");
        else        asm volatile("s_waitcnt vmcnt(0) lgkmcnt(0)" ::: "memory");
      }
      __builtin_amdgcn_s_barrier();
      // issue stage(it+3) into buf (it-1)&3 -- finished by all waves pre-barrier
      if (nt < 7) stageB(it + 3);
      else if (ch == 0) stageB(31);
      // ---- compute chunk (nt,ch) from buffer ch ----
      const u16* Bb = Bh4 + ch * (BN * CH);
      #pragma unroll
      for (int s = 0; s < 2; ++s) {
        #pragma unroll
        for (int ni = 0; ni < 2; ++ni) {
          int rowb = wn * 32 + ni * 16 + lr;
          int jp = (s * 4 + quad) ^ (rowb & 7);
          short8 bh = *(const short8*)&Bb[rowb * CH + jp * 8];
          #pragma unroll
          for (int mi = 0; mi < 2; ++mi)
            acc[mi][ni] = __builtin_amdgcn_mfma_f32_16x16x32_bf16(
                areg[ch][s][mi], bh, acc[mi][ni], 0, 0, 0);
        }
      }
      // ---- scoring at tile end (barrier-free; R5/R6-proven) ----
      if (ch == 3) {
        const int kc0 = nt * BN;
        #pragma unroll
        for (int mi = 0; mi < 2; ++mi)
          #pragma unroll
          for (int r = 0; r < 4; ++r) {
            const int slot = mi * 4 + r;
            const int row = wm * 32 + mi * 16 + quad * 4 + r;
            const float z2r = z2s[row];
            float dqv[2];
            #pragma unroll
            for (int ni = 0; ni < 2; ++ni)
              dqv[ni] = __fsub_rn(__fadd_rn(z2r, e2all[kc0 + wn * 32 + ni * 16 + lr]),
                                  __fmul_rn(2.f, acc[mi][ni][r]));
            float mm = fminf(dqv[0], dqv[1]);
            #pragma unroll
            for (int off = 1; off < 16; off <<= 1)
              mm = fminf(mm, __shfl_xor(mm, off));
            if (lr == 0) atomicMin(&Mlds[row], __float_as_uint(mm));
            float Mst = __uint_as_float(Mlds[row]);  // stale upper bound
            float base = fminf(mm, Mst);
            float thr = fmaf(base, TC_FACT, base);
            #pragma unroll
            for (int ni = 0; ni < 2; ++ni) {
              float dq = dqv[ni];
              int col = kc0 + wn * 32 + ni * 16 + lr;
              // strict < keeps first (smallest col) on ties; cols ascend
              if (dq < v1[slot]) { v1[slot] = dq; i1f[slot] = (float)col; }
              if (dq < thr) {
                unsigned pp = atomicAdd(&cntl[row], 1u);
                if (pp < CAP_BIG) {
                  lval[row * CAP_BIG + pp] = dq;
                  lidx[row * CAP_BIG + pp] = (u16)col;
                }
              }
              acc[mi][ni][r] = 0.f;   // reset for next tile
            }
          }
      }
    }
  }

  // ---- butterfly top-1 merge over the 16 col lanes (lr) ----
  #pragma unroll
  for (int off = 1; off < 16; off <<= 1) {
    #pragma unroll
    for (int s = 0; s < 8; ++s) {
      float ov1 = __shfl_xor(v1[s], off);
      float oi1 = __shfl_xor(i1f[s], off);
      bool take = (ov1 < v1[s]) || (ov1 == v1[s] && oi1 < i1f[s]);
      if (take) { v1[s] = ov1; i1f[s] = oi1; }
    }
  }
  // ---- per-wave (col-quarter) results to LDS (alias dead B bufs), merge ----
  __syncthreads();   // all waves done with compute + list appends
  float* mv1 = (float*)Bh4;        // [4][64]
  float* mi1 = mv1 + 4 * BM;
  if (lr == 0) {
    #pragma unroll
    for (int mi = 0; mi < 2; ++mi)
      #pragma unroll
      for (int r = 0; r < 4; ++r) {
        int slot = mi * 4 + r;
        int row = wm * 32 + mi * 16 + quad * 4 + r;   // 0..63
        mv1[wn * BM + row] = v1[slot];
        mi1[wn * BM + row] = i1f[slot];
      }
  }
  __syncthreads();
  if (t < BM) {
    float b1 = mv1[t], bi = mi1[t];
    #pragma unroll
    for (int qd = 1; qd < 4; ++qd) {
      float c1 = mv1[qd * BM + t], ci = mi1[qd * BM + t];
      if (c1 < b1 || (c1 == b1 && ci < bi)) { b1 = c1; bi = ci; }
    }
    out_idx[row0 + t] = bi;    // provisional winner (fixup overwrites flagged)
    // filter collected candidates against the final row min
    unsigned raw = cntl[t];
    float tf = fmaf(b1, TF_FACT, b1);
    int c = 0;
    u16 keep[CAP];
    bool ovf = raw > (unsigned)CAP_BIG;
    if (!ovf) {
      for (unsigned j = 0; j < raw; ++j) {
        if (lval[t * CAP_BIG + j] <= tf) {
          if (c < CAP) keep[c] = lidx[t * CAP_BIG + j];
          ++c;
        }
      }
      if (c > CAP) ovf = true;
    }
    if (ovf) {
      int o = atomicAdd(&qarr[1], 1);          // OV queue, top-down
      qarr[2 + NN - 1 - o] = row0 + t;
    } else if (c > 1) {
      int q = atomicAdd(&qarr[0], 1);          // list queue, bottom-up
      qarr[2 + q] = (row0 + t) | (c << 16);
      #pragma unroll
      for (int j = 0; j < CAP; ++j)
        cand[(size_t)q * CAP + j] = (j < c) ? keep[j] : (u16)0;
    }
  }
}

// ---------- fixup: exact f64-rounded f32 dots for listed candidates ----------
__global__ __launch_bounds__(256)
void fixup_k(const float* __restrict__ z, const float* __restrict__ emb,
             const float* __restrict__ e2np, const float* __restrict__ z2np,
             const int* __restrict__ qarr, const u16* __restrict__ cand,
             float* __restrict__ out_idx) {
  int qcnt = qarr[0];
  if (qcnt > NN) qcnt = NN;
  const int t = threadIdx.x;
  const int lane = t & 63, w = t >> 6;
  for (int q = blockIdx.x * 4 + w; q < qcnt; q += gridDim.x * 4) {
    int e = qarr[2 + q];
    int n = e & 0xffff;
    int c = e >> 16;
    int b = n >> 12, s = n & (SS - 1);
    float z2 = z2np[n];
    const float* zb = z + (((size_t)b * C) << 12) + s;
    float4 zv;
    zv.x = zb[((size_t)(lane * 4 + 0)) << 12];
    zv.y = zb[((size_t)(lane * 4 + 1)) << 12];
    zv.z = zb[((size_t)(lane * 4 + 2)) << 12];
    zv.w = zb[((size_t)(lane * 4 + 3)) << 12];
    float bestd = 3.4e38f;
    int besti = 0x7fffffff;
    for (int j = 0; j < c; ++j) {
      int kk = (int)cand[(size_t)q * CAP + j];
      const float4 ev = *(const float4*)&emb[(size_t)kk * C + lane * 4];
      double acc = (double)zv.x * (double)ev.x;
      acc = fma((double)zv.y, (double)ev.y, acc);
      acc = fma((double)zv.z, (double)ev.z, acc);
      acc = fma((double)zv.w, (double)ev.w, acc);
      #pragma unroll
      for (int off = 32; off; off >>= 1) acc += __shfl_xor(acc, off);
      float g  = (float)acc;           // correctly-rounded f32 dot
      float t1 = __fadd_rn(z2, e2np[kk]);
      float d  = __fsub_rn(t1, __fmul_rn(2.f, g));
      if (d < bestd || (d == bestd && kk < besti)) { bestd = d; besti = kk; }
    }
    if (lane == 0) out_idx[n] = (float)besti;
  }
}

// ---------- fixov: block-parallel exact full scan for OV rows ----------
__global__ __launch_bounds__(256)
void fixov_k(const float* __restrict__ z, const float* __restrict__ emb,
             const float* __restrict__ e2np, const float* __restrict__ z2np,
             const int* __restrict__ qarr, float* __restrict__ out_idx) {
  __shared__ float zrow[C];
  __shared__ float bv[4];
  __shared__ int   bx[4];
  int novr = qarr[1];
  if (novr > NN) novr = NN;
  const int t = threadIdx.x;
  const int lane = t & 63, w = t >> 6;
  for (int o = blockIdx.x; o < novr; o += gridDim.x) {
    int n = qarr[2 + NN - 1 - o];
    int b = n >> 12, s = n & (SS - 1);
    __syncthreads();   // prior iter's zrow readers done
    zrow[t] = z[((size_t)(b * C + t) << 12) + s];
    __syncthreads();
    float z2 = z2np[n];
    float best = 3.4e38f; int besti = 0x7fffffff;
    for (int kk = t; kk < K; kk += 256) {
      const float* er = emb + (size_t)kk * C;
      double a0 = 0.0, a1 = 0.0, a2 = 0.0, a3 = 0.0;
      for (int c = 0; c < C; c += 4) {
        a0 = fma((double)zrow[c + 0], (double)er[c + 0], a0);
        a1 = fma((double)zrow[c + 1], (double)er[c + 1], a1);
        a2 = fma((double)zrow[c + 2], (double)er[c + 2], a2);
        a3 = fma((double)zrow[c + 3], (double)er[c + 3], a3);
      }
      float g = (float)((a0 + a1) + (a2 + a3));
      float t1 = __fadd_rn(z2, e2np[kk]);
      float d  = __fsub_rn(t1, __fmul_rn(2.f, g));
      if (d < best || (d == best && kk < besti)) { best = d; besti = kk; }
    }
    #pragma unroll
    for (int off = 32; off; off >>= 1) {
      float ov = __shfl_down(best, off);
      int   oi = __shfl_down(besti, off);
      if (ov < best || (ov == best && oi < besti)) { best = ov; besti = oi; }
    }
    if (lane == 0) { bv[w] = best; bx[w] = besti; }
    __syncthreads();
    if (t == 0) {
      #pragma unroll
      for (int w2 = 1; w2 < 4; ++w2)
        if (bv[w2] < best || (bv[w2] == best && bx[w2] < besti)) {
          best = bv[w2]; besti = bx[w2];
        }
      out_idx[n] = (float)besti;
    }
  }
}

// ---------- gather via LDS-staged emb rows + loss + histogram ----------
#define GROWS 64
__global__ __launch_bounds__(256)
void gather2_k(const float* __restrict__ z, const float* __restrict__ emb,
               float* __restrict__ out, float* __restrict__ ws,
               float* __restrict__ counts) {
  __shared__ float eb[GROWS * 257];
  __shared__ int idxs[GROWS];
  __shared__ float sc[4];
  const int t = threadIdx.x;
  const int n0 = blockIdx.x * GROWS;
  const int b = n0 >> 12;
  const int s0 = n0 & (SS - 1);
  if (t < GROWS) {
    int id = (int)out[OUT_IDX + n0 + t];
    idxs[t] = id;
    atomicAdd(&counts[id], 1.0f);
  }
  __syncthreads();
  #pragma unroll
  for (int i = 0; i < 16; ++i) {
    int q = i * 256 + t;
    int row = q >> 6, c4 = q & 63;
    float4 v = *(const float4*)&emb[(size_t)idxs[row] * C + c4 * 4];
    int base = row * 257 + c4 * 4;
    eb[base + 0] = v.x; eb[base + 1] = v.y;
    eb[base + 2] = v.z; eb[base + 3] = v.w;
  }
  __syncthreads();
  const int sl = t & 63, cg = t >> 6;
  const float* zb = z + (size_t)b * C * SS + s0 + sl;
  float* ob = out + (size_t)b * C * SS + s0 + sl;
  float l = 0.f;
  #pragma unroll 4
  for (int i = 0; i < 64; ++i) {
    int c = cg * 64 + i;
    float q = eb[sl * 257 + c];
    float zv = zb[(size_t)c * SS];
    float d = q - zv;
    l += d * d;
    ob[(size_t)c * SS] = q;
  }
  #pragma unroll
  for (int off = 32; off; off >>= 1) l += __shfl_down(l, off);
  int lane = t & 63, w = t >> 6;
  if (lane == 0) sc[w] = l;
  __syncthreads();
  if (t == 0)
    atomicAdd(&ws[WS_LOSS], sc[0] + sc[1] + sc[2] + sc[3]);
}

// ---------- finalize scalars ----------
__global__ void finalize_k(const float* __restrict__ ws, float* __restrict__ out) {
  __shared__ float sc[8];
  int t = threadIdx.x;
  float ent = 0.f;
  #pragma unroll
  for (int k = t; k < K; k += 256) {
    float em = ws[WS_CNT + k] * (1.0f / NN);
    ent += em * logf(em + 1e-10f);
  }
  float zd = ws[WS_ZSUM + t] * ws[WS_ESUM + t];
  #pragma unroll
  for (int off = 32; off; off >>= 1) {
    ent += __shfl_down(ent, off);
    zd  += __shfl_down(zd, off);
  }
  int lane = t & 63, w = t >> 6;
  if (lane == 0) { sc[w] = ent; sc[4 + w] = zd; }
  __syncthreads();
  if (t == 0) {
    ent = sc[0] + sc[1] + sc[2] + sc[3];
    zd  = sc[4] + sc[5] + sc[6] + sc[7];
    out[OUT_LOSS] = 1.25f * ws[WS_LOSS] * (1.0f / ZQ_ELEMS);
    out[OUT_PERP] = expf(-ent);
    out[OUT_MD]   = ws[WS_SZ2] * (1.0f / NN) + ws[WS_SE2] * (1.0f / K)
                  - 2.0f * zd * (1.0f / ((float)NN * (float)K));
  }
}

extern "C" void kernel_launch(void* const* d_in, const int* in_sizes, int n_in,
                              void* d_out, int out_size, void* d_ws, size_t ws_size,
                              hipStream_t stream) {
  const float* z   = (const float*)d_in[0];
  const float* emb = (const float*)d_in[1];
  float* out = (float*)d_out;
  float* ws  = (float*)d_ws;
  int* qarr = (int*)(ws + WS_FLG);
  u16* cand = (u16*)(ws + WS_CAND);
  u16* eh_g = (u16*)(ws + WS_EH);
  // zh lives in d_out's zq region; overwritten by gather2_k at the end.
  u16* zh_g = (u16*)d_out;
  (void)in_sizes; (void)n_in; (void)out_size; (void)ws_size;

  hipMemsetAsync(d_ws, 0, WS_E2R * sizeof(float), stream);
  hipMemsetAsync(ws + WS_FLG, 0, 2 * sizeof(int), stream);
  emb_prep_k<<<64, 256, 0, stream>>>(emb, ws, eh_g);
  prep_z_k<<<NN / MROWS, 256, 0, stream>>>(z, ws, zh_g);
  size_t lds = (size_t)(4 * BN * CH) * sizeof(u16)
             + (size_t)(K + BM + BM * CAP_BIG) * sizeof(float)
             + (size_t)(2 * BM) * sizeof(unsigned)
             + (size_t)(BM * CAP_BIG) * sizeof(u16);
  vq_mfma_k<<<NN / BM, 512, lds, stream>>>(zh_g, eh_g,
                                           ws + WS_E2R, ws + WS_Z2N,
                                           out + OUT_IDX, qarr, cand);
  fixup_k<<<2048, 256, 0, stream>>>(z, emb, ws + WS_E2R, ws + WS_Z2N,
                                    qarr, cand, out + OUT_IDX);
  fixov_k<<<512, 256, 0, stream>>>(z, emb, ws + WS_E2R, ws + WS_Z2N,
                                   qarr, out + OUT_IDX);
  gather2_k<<<NN / GROWS, 256, 0, stream>>>(z, emb, out, ws, ws + WS_CNT);
  finalize_k<<<1, 256, 0, stream>>>(ws, out);
}

// Round 9
// 222.038 us; speedup vs baseline: 1.1796x; 1.1796x over previous
//
#include <hip/hip_runtime.h>
#include <math.h>

// Problem constants
#define C 256
#define K 1024
#define SS 4096          // 16*16*16 spatial
#define NB 8             // batch
#define NN 32768         // NB*SS rows
#define ZQ_ELEMS 8388608 // NB*C*SS
#define OUT_LOSS 8388608
#define OUT_PERP 8388609
#define OUT_IDX  8388610
#define OUT_MD   8421378

// workspace float layout
#define WS_SZ2   0       // sum z^2 (scalar)
#define WS_SE2   1       // sum e^2 (scalar)
#define WS_LOSS  2       // sum (zq-z)^2 (scalar)
#define WS_ZSUM  8       // [256] column sums of zf
#define WS_ESUM  264     // [256] column sums of emb
#define WS_CNT   520     // [1024] histogram (float)
#define WS_E2R   1544    // [1024] ||e_k||^2, numpy-pairwise f32
#define WS_Z2N   2568    // [32768] ||z_n||^2, numpy-pairwise f32
#define WS_FLG   35336   // int region: [0]=list cnt, [1]=ov cnt, [2..2+NN) entries
#define WS_EH    68608   // [1024*256] u16 emb-hi
#define WS_CAND  330752  // [NN*4] u16 candidate code indices per queue slot

// Candidate machinery: the reference computes d = fl(fl(z2+e2) - fl(2g)).
// Single-pass bf16 MFMA: per-element err rms ~9e-7 -> dot sigma ~1.4e-5 ->
// d-shift sigma ~2.9e-5. Argmin containment needs keep >= 2*s_max; s_max
// over 3.4e7 dots ~5.4 sigma -> keep >= 10.8 sigma. keep = 14 sigma
// (TF 1.6e-6 rel ~ 4.1e-4 at d~256), collect = 16 sigma (TC 1.8e-6).
// Exact-f64 fixup arbitrates all near-ties; OV rows get a block-parallel
// full scan. (R5/R6/R7 passed with these exact windows/queues.)
#define TC_FACT 1.8e-6f
#define TF_FACT 1.6e-6f
#define CAP 4            // max candidates per flagged row in global queue
#define CAP_BIG 24       // LDS collection capacity per row
#define OV 7             // sentinel: row went to the OV queue

typedef __attribute__((ext_vector_type(8))) short short8;
typedef __attribute__((ext_vector_type(4))) float f32x4;
typedef unsigned short u16;

__device__ inline u16 f2bf(float x) {  // f32 -> bf16 RNE
  unsigned u = __float_as_uint(x);
  unsigned r = (u + 0x7fffu + ((u >> 16) & 1u)) >> 16;
  return (u16)r;
}
__device__ inline float bf2f(u16 h) { return __uint_as_float(((unsigned)h) << 16); }

// async global->LDS 16B: LDS dest is wave-uniform base + lane*16 (linear);
// swizzle is applied on the per-lane GLOBAL address instead (m173 pattern).
__device__ __forceinline__ void gl_lds16(const u16* g, u16* l) {
  __builtin_amdgcn_global_load_lds(
      (const __attribute__((address_space(1))) unsigned int*)g,
      (__attribute__((address_space(3))) unsigned int*)l,
      16, 0, 0);
}

// ---- numpy pairwise f32 sum of squares, 256 contiguous elements ----
__device__ inline float np_sumsq_256(const float* __restrict__ a) {
  float tot = 0.f;
  #pragma unroll
  for (int h = 0; h < 2; ++h) {
    const float* p = a + 128 * h;
    float r[8];
    #pragma unroll
    for (int j = 0; j < 8; ++j) r[j] = __fmul_rn(p[j], p[j]);
    for (int i = 8; i < 128; i += 8) {
      #pragma unroll
      for (int j = 0; j < 8; ++j) {
        float v = p[i + j];
        r[j] = __fadd_rn(r[j], __fmul_rn(v, v));
      }
    }
    float s01 = __fadd_rn(r[0], r[1]);
    float s23 = __fadd_rn(r[2], r[3]);
    float s45 = __fadd_rn(r[4], r[5]);
    float s67 = __fadd_rn(r[6], r[7]);
    float res = __fadd_rn(__fadd_rn(s01, s23), __fadd_rn(s45, s67));
    tot = (h == 0) ? res : __fadd_rn(tot, res);
  }
  return tot;
}

// ---------- emb prep: bf16 eh, e2[k], col sums, Se2 ----------
__global__ __launch_bounds__(256)
void emb_prep_k(const float* __restrict__ emb, float* __restrict__ ws,
                u16* __restrict__ eh) {
  int r0 = blockIdx.x * 16;   // 64 blocks x 16 rows
  int t = threadIdx.x;
  float s = 0.f;
  #pragma unroll
  for (int i = 0; i < 16; ++i) {
    size_t idx = (size_t)(r0 + i) * C + t;
    float v = emb[idx];
    s += v;
    eh[idx] = f2bf(v);
  }
  atomicAdd(&ws[WS_ESUM + t], s);
  if (t < 16) {
    float e2 = np_sumsq_256(emb + (size_t)(r0 + t) * C);
    ws[WS_E2R + r0 + t] = e2;
    atomicAdd(&ws[WS_SE2], e2);
  }
}

#define MROWS 64
#define ZS_STRIDE 260

// ---------- one pass over z: zsum[c], Sz2, z2np[n], bf16 zh ----------
__global__ __launch_bounds__(256)
void prep_z_k(const float* __restrict__ z, float* __restrict__ ws,
              u16* __restrict__ zh_g) {
  __shared__ float zs[MROWS * ZS_STRIDE];
  const int t = threadIdx.x;
  const int n0 = blockIdx.x * MROWS;
  const int b = n0 / SS;
  const int s0 = n0 % SS;
  {
    const int sl = t & 63, cg = t >> 6;
    const float* zb = z + (size_t)b * C * SS + s0 + sl;
    #pragma unroll
    for (int i = 0; i < 16; ++i) {
      int c = (cg * 16 + i) * 4;
      float4 v;
      v.x = zb[(size_t)(c + 0) * SS];
      v.y = zb[(size_t)(c + 1) * SS];
      v.z = zb[(size_t)(c + 2) * SS];
      v.w = zb[(size_t)(c + 3) * SS];
      *(float4*)&zs[sl * ZS_STRIDE + c] = v;
    }
  }
  __syncthreads();
  // column sums
  {
    float s = 0.f;
    #pragma unroll 8
    for (int r = 0; r < MROWS; ++r) s += zs[r * ZS_STRIDE + t];
    atomicAdd(&ws[WS_ZSUM + t], s);
  }
  // bf16, lane-linear coalesced short8 stores
  {
    #pragma unroll
    for (int i = 0; i < 8; ++i) {
      int q = i * 256 + t;          // short8 chunk 0..2047
      int row = q >> 5;             // 0..63
      int c0 = (q & 31) * 8;
      float4 va = *(const float4*)&zs[row * ZS_STRIDE + c0];
      float4 vb = *(const float4*)&zs[row * ZS_STRIDE + c0 + 4];
      float f[8] = {va.x, va.y, va.z, va.w, vb.x, vb.y, vb.z, vb.w};
      short8 hv;
      #pragma unroll
      for (int j = 0; j < 8; ++j) hv[j] = (short)f2bf(f[j]);
      *(short8*)&zh_g[(size_t)(n0 + row) * C + c0] = hv;
    }
  }
  // z2 (numpy-pairwise) + Sz2
  if (t < MROWS) {
    float z2 = np_sumsq_256(&zs[t * ZS_STRIDE]);
    ws[WS_Z2N + n0 + t] = z2;
    #pragma unroll
    for (int off = 32; off; off >>= 1) z2 += __shfl_down(z2, off);
    if (t == 0) atomicAdd(&ws[WS_SZ2], z2);
  }
}

// ---------- main: single-pass bf16 MFMA, 8-wave blocks, depth-3 pipeline ----------
// R9: R8's replay-divergence was a rule-#18 race: asm s_waitcnt + raw
// s_barrier are NOT compiler memory fences -- hipcc may hoist/sink LDS reads
// (and the gl_lds DMA issue) across them, so a wave could read a B buffer
// before its stage landed (timing-dependent wrong argmin on some replays).
// Fix: __builtin_amdgcn_sched_barrier(0) BEFORE the waitcnt (nothing sinks
// past) and AFTER the s_barrier (nothing hoists above). Zero runtime cost.
// Rest unchanged from R8: wave layout 4x2 (16 rows x 64 cols/wave, areg
// [4][2]=32 VGPR, demand ~90), launch_bounds(512,2) (= 2 blocks/CU -> VGPR
// cap 128, no spill; R7's (512,4) meant 4 blocks/CU -> 64 cap -> spills).
// B staged via global_load_lds into 4 buffers, depth-3, counted vmcnt.
#define BM 64
#define BN 128
#define CH 64

__global__ __launch_bounds__(512, 2)
void vq_mfma_k(const u16* __restrict__ zh_g, const u16* __restrict__ eh_g,
               const float* __restrict__ e2row, const float* __restrict__ z2np,
               float* __restrict__ out_idx,
               int* __restrict__ qarr, u16* __restrict__ cand) {
  extern __shared__ u16 smem_u16[];
  u16* Bh4 = smem_u16;                         // [4][128][64] u16, swizzled
  float* e2all = (float*)(Bh4 + 4 * BN * CH);  // [1024]
  float* z2s  = e2all + K;                     // [64]
  float* lval = z2s + BM;                      // [64][CAP_BIG] candidate dq
  unsigned* Mlds = (unsigned*)(lval + BM * CAP_BIG);  // [64] running row min
  unsigned* cntl = Mlds + BM;                  // [64] append counters
  u16* lidx = (u16*)(cntl + BM);               // [64][CAP_BIG] candidate idx

  const int t = threadIdx.x;
  const int lane = t & 63;
  const int wid = t >> 6;          // 0..7
  const int wm = wid >> 1;         // 0..3 : 16-row group
  const int wn = wid & 1;          // 0..1 : 64-col half
  const int quad = lane >> 4, lr = lane & 15;
  const int row0 = blockIdx.x * BM;
  // per-lane pre-swizzled source offset within an 8-row group
  const int wrow = lane >> 3;
  const int pl = wrow * C + ((lane & 7) ^ wrow) * 8;

  // ---- prologue: LDS scalars, A->regs, first three B stages ----
  #pragma unroll
  for (int i = 0; i < 2; ++i) e2all[i * 512 + t] = e2row[i * 512 + t];
  if (t < BM) {
    z2s[t] = z2np[row0 + t];
    Mlds[t] = 0x7F800000u;  // +inf (positive floats order as uints)
    cntl[t] = 0u;
  }
  short8 areg[4][2];   // [ch][s] : 32 VGPR, this wave's 16 rows
  #pragma unroll
  for (int ch = 0; ch < 4; ++ch)
    #pragma unroll
    for (int s = 0; s < 2; ++s)
      areg[ch][s] = *(const short8*)
        &zh_g[(size_t)(row0 + wm * 16 + lr) * C + ch * CH + (s * 4 + quad) * 8];

  auto stageB = [&](int j) {   // stage chunk j -> buffer j&3 (2 loads/wave)
    u16* Bb = Bh4 + (j & 3) * (BN * CH);
    const u16* srcb = eh_g + (size_t)(j >> 2) * (BN * C) + (j & 3) * CH;
    #pragma unroll
    for (int i = 0; i < 2; ++i) {
      int grow = (wid * 2 + i) * 8;
      gl_lds16(&srcb[(size_t)grow * C + pl], &Bb[grow * CH]);
    }
  };
  stageB(0);
  stageB(1);
  stageB(2);

  float v1[4], i1f[4];
  #pragma unroll
  for (int s = 0; s < 4; ++s) { v1[s] = 3.4e38f; i1f[s] = 0.f; }
  f32x4 acc[4];
  #pragma unroll
  for (int ni = 0; ni < 4; ++ni) acc[ni] = (f32x4){0.f, 0.f, 0.f, 0.f};

  for (int nt = 0; nt < 8; ++nt) {
    #pragma unroll
    for (int ch = 0; ch < 4; ++ch) {
      const int it = nt * 4 + ch;
      // --- pinned sync point (rule #18): nothing sinks below this line ---
      __builtin_amdgcn_sched_barrier(0);
      // wait: own stage(it) landed (outstanding {it..it+2} = 6 -> vmcnt(4));
      // lgkmcnt(0) publishes LDS init/scoring writes at the barrier.
      if (ch < 2) {
        asm volatile("s_waitcnt vmcnt(4) lgkmcnt(0)" ::: "memory");
      } else if (ch == 2) {
        if (nt < 7) asm volatile("s_waitcnt vmcnt(4) lgkmcnt(0)" ::: "memory");
        else        asm volatile("s_waitcnt vmcnt(2) lgkmcnt(0)" ::: "memory");
      } else {
        if (nt < 7) asm volatile("s_waitcnt vmcnt(4) lgkmcnt(0)" ::: "memory");
        else        asm volatile("s_waitcnt vmcnt(0) lgkmcnt(0)" ::: "memory");
      }
      __builtin_amdgcn_s_barrier();
      // --- nothing hoists above this line ---
      __builtin_amdgcn_sched_barrier(0);
      // issue stage(it+3) into buf (it-1)&3 -- finished by all waves pre-barrier
      if (nt < 7) stageB(it + 3);
      else if (ch == 0) stageB(31);
      // ---- compute chunk (nt,ch) from buffer ch ----
      const u16* Bb = Bh4 + ch * (BN * CH);
      #pragma unroll
      for (int s = 0; s < 2; ++s) {
        #pragma unroll
        for (int ni = 0; ni < 4; ++ni) {
          int rowb = wn * 64 + ni * 16 + lr;
          int jp = (s * 4 + quad) ^ (rowb & 7);
          short8 bh = *(const short8*)&Bb[rowb * CH + jp * 8];
          acc[ni] = __builtin_amdgcn_mfma_f32_16x16x32_bf16(
              areg[ch][s], bh, acc[ni], 0, 0, 0);
        }
      }
      // ---- scoring at tile end (barrier-free; R5/R6-proven) ----
      if (ch == 3) {
        const int kc0 = nt * BN;
        #pragma unroll
        for (int r = 0; r < 4; ++r) {
          const int row = wm * 16 + quad * 4 + r;
          const float z2r = z2s[row];
          float dqv[4];
          #pragma unroll
          for (int ni = 0; ni < 4; ++ni)
            dqv[ni] = __fsub_rn(__fadd_rn(z2r, e2all[kc0 + wn * 64 + ni * 16 + lr]),
                                __fmul_rn(2.f, acc[ni][r]));
          float mm = fminf(fminf(dqv[0], dqv[1]), fminf(dqv[2], dqv[3]));
          #pragma unroll
          for (int off = 1; off < 16; off <<= 1)
            mm = fminf(mm, __shfl_xor(mm, off));
          if (lr == 0) atomicMin(&Mlds[row], __float_as_uint(mm));
          float Mst = __uint_as_float(Mlds[row]);  // stale upper bound
          float base = fminf(mm, Mst);
          float thr = fmaf(base, TC_FACT, base);
          #pragma unroll
          for (int ni = 0; ni < 4; ++ni) {
            float dq = dqv[ni];
            int col = kc0 + wn * 64 + ni * 16 + lr;
            // strict < keeps first (smallest col) on ties; cols ascend
            if (dq < v1[r]) { v1[r] = dq; i1f[r] = (float)col; }
            if (dq < thr) {
              unsigned pp = atomicAdd(&cntl[row], 1u);
              if (pp < CAP_BIG) {
                lval[row * CAP_BIG + pp] = dq;
                lidx[row * CAP_BIG + pp] = (u16)col;
              }
            }
            acc[ni][r] = 0.f;   // reset for next tile
          }
        }
      }
    }
  }

  // ---- butterfly top-1 merge over the 16 col lanes (lr) ----
  #pragma unroll
  for (int off = 1; off < 16; off <<= 1) {
    #pragma unroll
    for (int s = 0; s < 4; ++s) {
      float ov1 = __shfl_xor(v1[s], off);
      float oi1 = __shfl_xor(i1f[s], off);
      bool take = (ov1 < v1[s]) || (ov1 == v1[s] && oi1 < i1f[s]);
      if (take) { v1[s] = ov1; i1f[s] = oi1; }
    }
  }
  // ---- per-wave (col-half) results to LDS (alias dead B bufs), merge ----
  __syncthreads();   // real fence+barrier: all compute + appends + DMAs done
  float* mv1 = (float*)Bh4;        // [2][64]
  float* mi1 = mv1 + 2 * BM;
  if (lr == 0) {
    #pragma unroll
    for (int r = 0; r < 4; ++r) {
      int row = wm * 16 + quad * 4 + r;   // 0..63
      mv1[wn * BM + row] = v1[r];
      mi1[wn * BM + row] = i1f[r];
    }
  }
  __syncthreads();
  if (t < BM) {
    float a1 = mv1[t], ai = mi1[t];
    float c1 = mv1[BM + t], ci = mi1[BM + t];
    bool take = (c1 < a1) || (c1 == a1 && ci < ai);
    float b1 = take ? c1 : a1;
    float bi = take ? ci : ai;
    out_idx[row0 + t] = bi;    // provisional winner (fixup overwrites flagged)
    // filter collected candidates against the final row min
    unsigned raw = cntl[t];
    float tf = fmaf(b1, TF_FACT, b1);
    int c = 0;
    u16 keep[CAP];
    bool ovf = raw > (unsigned)CAP_BIG;
    if (!ovf) {
      for (unsigned j = 0; j < raw; ++j) {
        if (lval[t * CAP_BIG + j] <= tf) {
          if (c < CAP) keep[c] = lidx[t * CAP_BIG + j];
          ++c;
        }
      }
      if (c > CAP) ovf = true;
    }
    if (ovf) {
      int o = atomicAdd(&qarr[1], 1);          // OV queue, top-down
      qarr[2 + NN - 1 - o] = row0 + t;
    } else if (c > 1) {
      int q = atomicAdd(&qarr[0], 1);          // list queue, bottom-up
      qarr[2 + q] = (row0 + t) | (c << 16);
      #pragma unroll
      for (int j = 0; j < CAP; ++j)
        cand[(size_t)q * CAP + j] = (j < c) ? keep[j] : (u16)0;
    }
  }
}

// ---------- fixup: exact f64-rounded f32 dots for listed candidates ----------
__global__ __launch_bounds__(256)
void fixup_k(const float* __restrict__ z, const float* __restrict__ emb,
             const float* __restrict__ e2np, const float* __restrict__ z2np,
             const int* __restrict__ qarr, const u16* __restrict__ cand,
             float* __restrict__ out_idx) {
  int qcnt = qarr[0];
  if (qcnt > NN) qcnt = NN;
  const int t = threadIdx.x;
  const int lane = t & 63, w = t >> 6;
  for (int q = blockIdx.x * 4 + w; q < qcnt; q += gridDim.x * 4) {
    int e = qarr[2 + q];
    int n = e & 0xffff;
    int c = e >> 16;
    int b = n >> 12, s = n & (SS - 1);
    float z2 = z2np[n];
    const float* zb = z + (((size_t)b * C) << 12) + s;
    float4 zv;
    zv.x = zb[((size_t)(lane * 4 + 0)) << 12];
    zv.y = zb[((size_t)(lane * 4 + 1)) << 12];
    zv.z = zb[((size_t)(lane * 4 + 2)) << 12];
    zv.w = zb[((size_t)(lane * 4 + 3)) << 12];
    float bestd = 3.4e38f;
    int besti = 0x7fffffff;
    for (int j = 0; j < c; ++j) {
      int kk = (int)cand[(size_t)q * CAP + j];
      const float4 ev = *(const float4*)&emb[(size_t)kk * C + lane * 4];
      double acc = (double)zv.x * (double)ev.x;
      acc = fma((double)zv.y, (double)ev.y, acc);
      acc = fma((double)zv.z, (double)ev.z, acc);
      acc = fma((double)zv.w, (double)ev.w, acc);
      #pragma unroll
      for (int off = 32; off; off >>= 1) acc += __shfl_xor(acc, off);
      float g  = (float)acc;           // correctly-rounded f32 dot
      float t1 = __fadd_rn(z2, e2np[kk]);
      float d  = __fsub_rn(t1, __fmul_rn(2.f, g));
      if (d < bestd || (d == bestd && kk < besti)) { bestd = d; besti = kk; }
    }
    if (lane == 0) out_idx[n] = (float)besti;
  }
}

// ---------- fixov: block-parallel exact full scan for OV rows ----------
__global__ __launch_bounds__(256)
void fixov_k(const float* __restrict__ z, const float* __restrict__ emb,
             const float* __restrict__ e2np, const float* __restrict__ z2np,
             const int* __restrict__ qarr, float* __restrict__ out_idx) {
  __shared__ float zrow[C];
  __shared__ float bv[4];
  __shared__ int   bx[4];
  int novr = qarr[1];
  if (novr > NN) novr = NN;
  const int t = threadIdx.x;
  const int lane = t & 63, w = t >> 6;
  for (int o = blockIdx.x; o < novr; o += gridDim.x) {
    int n = qarr[2 + NN - 1 - o];
    int b = n >> 12, s = n & (SS - 1);
    __syncthreads();   // prior iter's zrow readers done
    zrow[t] = z[((size_t)(b * C + t) << 12) + s];
    __syncthreads();
    float z2 = z2np[n];
    float best = 3.4e38f; int besti = 0x7fffffff;
    for (int kk = t; kk < K; kk += 256) {
      const float* er = emb + (size_t)kk * C;
      double a0 = 0.0, a1 = 0.0, a2 = 0.0, a3 = 0.0;
      for (int c = 0; c < C; c += 4) {
        a0 = fma((double)zrow[c + 0], (double)er[c + 0], a0);
        a1 = fma((double)zrow[c + 1], (double)er[c + 1], a1);
        a2 = fma((double)zrow[c + 2], (double)er[c + 2], a2);
        a3 = fma((double)zrow[c + 3], (double)er[c + 3], a3);
      }
      float g = (float)((a0 + a1) + (a2 + a3));
      float t1 = __fadd_rn(z2, e2np[kk]);
      float d  = __fsub_rn(t1, __fmul_rn(2.f, g));
      if (d < best || (d == best && kk < besti)) { best = d; besti = kk; }
    }
    #pragma unroll
    for (int off = 32; off; off >>= 1) {
      float ov = __shfl_down(best, off);
      int   oi = __shfl_down(besti, off);
      if (ov < best || (ov == best && oi < besti)) { best = ov; besti = oi; }
    }
    if (lane == 0) { bv[w] = best; bx[w] = besti; }
    __syncthreads();
    if (t == 0) {
      #pragma unroll
      for (int w2 = 1; w2 < 4; ++w2)
        if (bv[w2] < best || (bv[w2] == best && bx[w2] < besti)) {
          best = bv[w2]; besti = bx[w2];
        }
      out_idx[n] = (float)besti;
    }
  }
}

// ---------- gather via LDS-staged emb rows + loss + histogram ----------
#define GROWS 64
__global__ __launch_bounds__(256)
void gather2_k(const float* __restrict__ z, const float* __restrict__ emb,
               float* __restrict__ out, float* __restrict__ ws,
               float* __restrict__ counts) {
  __shared__ float eb[GROWS * 257];
  __shared__ int idxs[GROWS];
  __shared__ float sc[4];
  const int t = threadIdx.x;
  const int n0 = blockIdx.x * GROWS;
  const int b = n0 >> 12;
  const int s0 = n0 & (SS - 1);
  if (t < GROWS) {
    int id = (int)out[OUT_IDX + n0 + t];
    idxs[t] = id;
    atomicAdd(&counts[id], 1.0f);
  }
  __syncthreads();
  #pragma unroll
  for (int i = 0; i < 16; ++i) {
    int q = i * 256 + t;
    int row = q >> 6, c4 = q & 63;
    float4 v = *(const float4*)&emb[(size_t)idxs[row] * C + c4 * 4];
    int base = row * 257 + c4 * 4;
    eb[base + 0] = v.x; eb[base + 1] = v.y;
    eb[base + 2] = v.z; eb[base + 3] = v.w;
  }
  __syncthreads();
  const int sl = t & 63, cg = t >> 6;
  const float* zb = z + (size_t)b * C * SS + s0 + sl;
  float* ob = out + (size_t)b * C * SS + s0 + sl;
  float l = 0.f;
  #pragma unroll 4
  for (int i = 0; i < 64; ++i) {
    int c = cg * 64 + i;
    float q = eb[sl * 257 + c];
    float zv = zb[(size_t)c * SS];
    float d = q - zv;
    l += d * d;
    ob[(size_t)c * SS] = q;
  }
  #pragma unroll
  for (int off = 32; off; off >>= 1) l += __shfl_down(l, off);
  int lane = t & 63, w = t >> 6;
  if (lane == 0) sc[w] = l;
  __syncthreads();
  if (t == 0)
    atomicAdd(&ws[WS_LOSS], sc[0] + sc[1] + sc[2] + sc[3]);
}

// ---------- finalize scalars ----------
__global__ void finalize_k(const float* __restrict__ ws, float* __restrict__ out) {
  __shared__ float sc[8];
  int t = threadIdx.x;
  float ent = 0.f;
  #pragma unroll
  for (int k = t; k < K; k += 256) {
    float em = ws[WS_CNT + k] * (1.0f / NN);
    ent += em * logf(em + 1e-10f);
  }
  float zd = ws[WS_ZSUM + t] * ws[WS_ESUM + t];
  #pragma unroll
  for (int off = 32; off; off >>= 1) {
    ent += __shfl_down(ent, off);
    zd  += __shfl_down(zd, off);
  }
  int lane = t & 63, w = t >> 6;
  if (lane == 0) { sc[w] = ent; sc[4 + w] = zd; }
  __syncthreads();
  if (t == 0) {
    ent = sc[0] + sc[1] + sc[2] + sc[3];
    zd  = sc[4] + sc[5] + sc[6] + sc[7];
    out[OUT_LOSS] = 1.25f * ws[WS_LOSS] * (1.0f / ZQ_ELEMS);
    out[OUT_PERP] = expf(-ent);
    out[OUT_MD]   = ws[WS_SZ2] * (1.0f / NN) + ws[WS_SE2] * (1.0f / K)
                  - 2.0f * zd * (1.0f / ((float)NN * (float)K));
  }
}

extern "C" void kernel_launch(void* const* d_in, const int* in_sizes, int n_in,
                              void* d_out, int out_size, void* d_ws, size_t ws_size,
                              hipStream_t stream) {
  const float* z   = (const float*)d_in[0];
  const float* emb = (const float*)d_in[1];
  float* out = (float*)d_out;
  float* ws  = (float*)d_ws;
  int* qarr = (int*)(ws + WS_FLG);
  u16* cand = (u16*)(ws + WS_CAND);
  u16* eh_g = (u16*)(ws + WS_EH);
  // zh lives in d_out's zq region; overwritten by gather2_k at the end.
  u16* zh_g = (u16*)d_out;
  (void)in_sizes; (void)n_in; (void)out_size; (void)ws_size;

  hipMemsetAsync(d_ws, 0, WS_E2R * sizeof(float), stream);
  hipMemsetAsync(ws + WS_FLG, 0, 2 * sizeof(int), stream);
  emb_prep_k<<<64, 256, 0, stream>>>(emb, ws, eh_g);
  prep_z_k<<<NN / MROWS, 256, 0, stream>>>(z, ws, zh_g);
  size_t lds = (size_t)(4 * BN * CH) * sizeof(u16)
             + (size_t)(K + BM + BM * CAP_BIG) * sizeof(float)
             + (size_t)(2 * BM) * sizeof(unsigned)
             + (size_t)(BM * CAP_BIG) * sizeof(u16);
  vq_mfma_k<<<NN / BM, 512, lds, stream>>>(zh_g, eh_g,
                                           ws + WS_E2R, ws + WS_Z2N,
                                           out + OUT_IDX, qarr, cand);
  fixup_k<<<2048, 256, 0, stream>>>(z, emb, ws + WS_E2R, ws + WS_Z2N,
                                    qarr, cand, out + OUT_IDX);
  fixov_k<<<512, 256, 0, stream>>>(z, emb, ws + WS_E2R, ws + WS_Z2N,
                                   qarr, out + OUT_IDX);
  gather2_k<<<NN / GROWS, 256, 0, stream>>>(z, emb, out, ws, ws + WS_CNT);
  finalize_k<<<1, 256, 0, stream>>>(ws, out);
}

// Round 11
// 217.527 us; speedup vs baseline: 1.2040x; 1.0207x over previous
//
#include <hip/hip_runtime.h>
#include <math.h>

// Problem constants
#define C 256
#define K 1024
#define SS 4096          // 16*16*16 spatial
#define NB 8             // batch
#define NN 32768         // NB*SS rows
#define ZQ_ELEMS 8388608 // NB*C*SS
#define OUT_LOSS 8388608
#define OUT_PERP 8388609
#define OUT_IDX  8388610
#define OUT_MD   8421378

// workspace float layout
#define WS_SZ2   0       // sum z^2 (scalar)
#define WS_SE2   1       // sum e^2 (scalar)
#define WS_LOSS  2       // sum (zq-z)^2 (scalar)  [= sum of winner dq, R10]
#define WS_ZSUM  8       // [256] column sums of zf
#define WS_ESUM  264     // [256] column sums of emb
#define WS_CNT   520     // [1024] histogram (float)
#define WS_E2R   1544    // [1024] ||e_k||^2, numpy-pairwise f32
#define WS_Z2N   2568    // [32768] ||z_n||^2, numpy-pairwise f32
#define WS_FLG   35336   // int region: [0]=list cnt, [1]=ov cnt, [2..2+NN) entries
#define WS_EH    68608   // [1024*256] u16 emb-hi
#define WS_CAND  330752  // [NN*4] u16 candidate code indices per queue slot

// Candidate machinery: the reference computes d = fl(fl(z2+e2) - fl(2g)).
// Single-pass bf16 MFMA: per-element err rms ~9e-7 -> dot sigma ~1.4e-5 ->
// d-shift sigma ~2.9e-5. Argmin containment needs keep >= 2*s_max; s_max
// over 3.4e7 dots ~5.4 sigma -> keep >= 10.8 sigma. keep = 14 sigma
// (TF 1.6e-6 rel ~ 4.1e-4 at d~256), collect = 16 sigma (TC 1.8e-6).
// Exact-f64 fixup arbitrates all near-ties; OV rows get a block-parallel
// full scan. (R5/R6/R9 passed with these exact windows/queues.)
// R10: loss = sum_n d_n is accumulated in vq from the winner's dq (error
// <= ~6e-5/row -> <=2.4e-7 on the mean, far under tolerance), so gather2
// no longer reads z at all.
#define TC_FACT 1.8e-6f
#define TF_FACT 1.6e-6f
#define CAP 4            // max candidates per flagged row in global queue
#define CAP_BIG 24       // LDS collection capacity per row
#define OV 7             // sentinel: row went to the OV queue

typedef __attribute__((ext_vector_type(8))) short short8;
typedef __attribute__((ext_vector_type(4))) float f32x4;
typedef unsigned short u16;

__device__ inline u16 f2bf(float x) {  // f32 -> bf16 RNE
  unsigned u = __float_as_uint(x);
  unsigned r = (u + 0x7fffu + ((u >> 16) & 1u)) >> 16;
  return (u16)r;
}
__device__ inline float bf2f(u16 h) { return __uint_as_float(((unsigned)h) << 16); }

// async global->LDS 16B: LDS dest is wave-uniform base + lane*16 (linear);
// swizzle is applied on the per-lane GLOBAL address instead (m173 pattern).
__device__ __forceinline__ void gl_lds16(const u16* g, u16* l) {
  __builtin_amdgcn_global_load_lds(
      (const __attribute__((address_space(1))) unsigned int*)g,
      (__attribute__((address_space(3))) unsigned int*)l,
      16, 0, 0);
}

// ---- numpy pairwise f32 sum of squares, 256 contiguous elements ----
__device__ inline float np_sumsq_256(const float* __restrict__ a) {
  float tot = 0.f;
  #pragma unroll
  for (int h = 0; h < 2; ++h) {
    const float* p = a + 128 * h;
    float r[8];
    #pragma unroll
    for (int j = 0; j < 8; ++j) r[j] = __fmul_rn(p[j], p[j]);
    for (int i = 8; i < 128; i += 8) {
      #pragma unroll
      for (int j = 0; j < 8; ++j) {
        float v = p[i + j];
        r[j] = __fadd_rn(r[j], __fmul_rn(v, v));
      }
    }
    float s01 = __fadd_rn(r[0], r[1]);
    float s23 = __fadd_rn(r[2], r[3]);
    float s45 = __fadd_rn(r[4], r[5]);
    float s67 = __fadd_rn(r[6], r[7]);
    float res = __fadd_rn(__fadd_rn(s01, s23), __fadd_rn(s45, s67));
    tot = (h == 0) ? res : __fadd_rn(tot, res);
  }
  return tot;
}

// ---------- emb prep: bf16 eh, e2[k], col sums, Se2 ----------
__global__ __launch_bounds__(256)
void emb_prep_k(const float* __restrict__ emb, float* __restrict__ ws,
                u16* __restrict__ eh) {
  int r0 = blockIdx.x * 16;   // 64 blocks x 16 rows
  int t = threadIdx.x;
  float s = 0.f;
  #pragma unroll
  for (int i = 0; i < 16; ++i) {
    size_t idx = (size_t)(r0 + i) * C + t;
    float v = emb[idx];
    s += v;
    eh[idx] = f2bf(v);
  }
  atomicAdd(&ws[WS_ESUM + t], s);
  if (t < 16) {
    float e2 = np_sumsq_256(emb + (size_t)(r0 + t) * C);
    ws[WS_E2R + r0 + t] = e2;
    atomicAdd(&ws[WS_SE2], e2);
  }
}

#define MROWS 64
#define ZS_STRIDE 260

// ---------- one pass over z: zsum[c], Sz2, z2np[n], bf16 zh ----------
__global__ __launch_bounds__(256)
void prep_z_k(const float* __restrict__ z, float* __restrict__ ws,
              u16* __restrict__ zh_g) {
  __shared__ float zs[MROWS * ZS_STRIDE];
  const int t = threadIdx.x;
  const int n0 = blockIdx.x * MROWS;
  const int b = n0 / SS;
  const int s0 = n0 % SS;
  {
    const int sl = t & 63, cg = t >> 6;
    const float* zb = z + (size_t)b * C * SS + s0 + sl;
    #pragma unroll
    for (int i = 0; i < 16; ++i) {
      int c = (cg * 16 + i) * 4;
      float4 v;
      v.x = zb[(size_t)(c + 0) * SS];
      v.y = zb[(size_t)(c + 1) * SS];
      v.z = zb[(size_t)(c + 2) * SS];
      v.w = zb[(size_t)(c + 3) * SS];
      *(float4*)&zs[sl * ZS_STRIDE + c] = v;
    }
  }
  __syncthreads();
  // column sums
  {
    float s = 0.f;
    #pragma unroll 8
    for (int r = 0; r < MROWS; ++r) s += zs[r * ZS_STRIDE + t];
    atomicAdd(&ws[WS_ZSUM + t], s);
  }
  // bf16, lane-linear coalesced short8 stores
  {
    #pragma unroll
    for (int i = 0; i < 8; ++i) {
      int q = i * 256 + t;          // short8 chunk 0..2047
      int row = q >> 5;             // 0..63
      int c0 = (q & 31) * 8;
      float4 va = *(const float4*)&zs[row * ZS_STRIDE + c0];
      float4 vb = *(const float4*)&zs[row * ZS_STRIDE + c0 + 4];
      float f[8] = {va.x, va.y, va.z, va.w, vb.x, vb.y, vb.z, vb.w};
      short8 hv;
      #pragma unroll
      for (int j = 0; j < 8; ++j) hv[j] = (short)f2bf(f[j]);
      *(short8*)&zh_g[(size_t)(n0 + row) * C + c0] = hv;
    }
  }
  // z2 (numpy-pairwise) + Sz2
  if (t < MROWS) {
    float z2 = np_sumsq_256(&zs[t * ZS_STRIDE]);
    ws[WS_Z2N + n0 + t] = z2;
    #pragma unroll
    for (int off = 32; off; off >>= 1) z2 += __shfl_down(z2, off);
    if (t == 0) atomicAdd(&ws[WS_SZ2], z2);
  }
}

// ---------- main: single-pass bf16 MFMA, 8-wave blocks, depth-3 pipeline ----------
// (R9-proven structure.) Wave layout 4x2 (16 rows x 64 cols/wave, areg
// [4][2]=32 VGPR), launch_bounds(512,2) = 2 blocks/CU -> VGPR cap 128, no
// spill. B staged via global_load_lds into 4 buffers, depth-3, counted
// vmcnt + raw s_barrier, each sync point pinned with sched_barrier(0)
// (rule #18: asm waitcnt/s_barrier are not compiler fences).
// R10 adds: block loss reduction (sum of winner dq) -> one atomicAdd.
#define BM 64
#define BN 128
#define CH 64

__global__ __launch_bounds__(512, 2)
void vq_mfma_k(const u16* __restrict__ zh_g, const u16* __restrict__ eh_g,
               const float* __restrict__ e2row, const float* __restrict__ z2np,
               float* __restrict__ out_idx,
               int* __restrict__ qarr, u16* __restrict__ cand,
               float* __restrict__ loss_ws) {
  extern __shared__ u16 smem_u16[];
  u16* Bh4 = smem_u16;                         // [4][128][64] u16, swizzled
  float* e2all = (float*)(Bh4 + 4 * BN * CH);  // [1024]
  float* z2s  = e2all + K;                     // [64]
  float* lval = z2s + BM;                      // [64][CAP_BIG] candidate dq
  unsigned* Mlds = (unsigned*)(lval + BM * CAP_BIG);  // [64] running row min
  unsigned* cntl = Mlds + BM;                  // [64] append counters
  u16* lidx = (u16*)(cntl + BM);               // [64][CAP_BIG] candidate idx

  const int t = threadIdx.x;
  const int lane = t & 63;
  const int wid = t >> 6;          // 0..7
  const int wm = wid >> 1;         // 0..3 : 16-row group
  const int wn = wid & 1;          // 0..1 : 64-col half
  const int quad = lane >> 4, lr = lane & 15;
  const int row0 = blockIdx.x * BM;
  // per-lane pre-swizzled source offset within an 8-row group
  const int wrow = lane >> 3;
  const int pl = wrow * C + ((lane & 7) ^ wrow) * 8;

  // ---- prologue: LDS scalars, A->regs, first three B stages ----
  #pragma unroll
  for (int i = 0; i < 2; ++i) e2all[i * 512 + t] = e2row[i * 512 + t];
  if (t < BM) {
    z2s[t] = z2np[row0 + t];
    Mlds[t] = 0x7F800000u;  // +inf (positive floats order as uints)
    cntl[t] = 0u;
  }
  short8 areg[4][2];   // [ch][s] : 32 VGPR, this wave's 16 rows
  #pragma unroll
  for (int ch = 0; ch < 4; ++ch)
    #pragma unroll
    for (int s = 0; s < 2; ++s)
      areg[ch][s] = *(const short8*)
        &zh_g[(size_t)(row0 + wm * 16 + lr) * C + ch * CH + (s * 4 + quad) * 8];

  auto stageB = [&](int j) {   // stage chunk j -> buffer j&3 (2 loads/wave)
    u16* Bb = Bh4 + (j & 3) * (BN * CH);
    const u16* srcb = eh_g + (size_t)(j >> 2) * (BN * C) + (j & 3) * CH;
    #pragma unroll
    for (int i = 0; i < 2; ++i) {
      int grow = (wid * 2 + i) * 8;
      gl_lds16(&srcb[(size_t)grow * C + pl], &Bb[grow * CH]);
    }
  };
  stageB(0);
  stageB(1);
  stageB(2);

  float v1[4], i1f[4];
  #pragma unroll
  for (int s = 0; s < 4; ++s) { v1[s] = 3.4e38f; i1f[s] = 0.f; }
  f32x4 acc[4];
  #pragma unroll
  for (int ni = 0; ni < 4; ++ni) acc[ni] = (f32x4){0.f, 0.f, 0.f, 0.f};

  for (int nt = 0; nt < 8; ++nt) {
    #pragma unroll
    for (int ch = 0; ch < 4; ++ch) {
      const int it = nt * 4 + ch;
      // --- pinned sync point (rule #18): nothing sinks below this line ---
      __builtin_amdgcn_sched_barrier(0);
      // wait: own stage(it) landed (outstanding {it..it+2} = 6 -> vmcnt(4));
      // lgkmcnt(0) publishes LDS init/scoring writes at the barrier.
      if (ch < 2) {
        asm volatile("s_waitcnt vmcnt(4) lgkmcnt(0)" ::: "memory");
      } else if (ch == 2) {
        if (nt < 7) asm volatile("s_waitcnt vmcnt(4) lgkmcnt(0)" ::: "memory");
        else        asm volatile("s_waitcnt vmcnt(2) lgkmcnt(0)" ::: "memory");
      } else {
        if (nt < 7) asm volatile("s_waitcnt vmcnt(4) lgkmcnt(0)" ::: "memory");
        else        asm volatile("s_waitcnt vmcnt(0) lgkmcnt(0)" ::: "memory");
      }
      __builtin_amdgcn_s_barrier();
      // --- nothing hoists above this line ---
      __builtin_amdgcn_sched_barrier(0);
      // issue stage(it+3) into buf (it-1)&3 -- finished by all waves pre-barrier
      if (nt < 7) stageB(it + 3);
      else if (ch == 0) stageB(31);
      // ---- compute chunk (nt,ch) from buffer ch ----
      const u16* Bb = Bh4 + ch * (BN * CH);
      #pragma unroll
      for (int s = 0; s < 2; ++s) {
        #pragma unroll
        for (int ni = 0; ni < 4; ++ni) {
          int rowb = wn * 64 + ni * 16 + lr;
          int jp = (s * 4 + quad) ^ (rowb & 7);
          short8 bh = *(const short8*)&Bb[rowb * CH + jp * 8];
          acc[ni] = __builtin_amdgcn_mfma_f32_16x16x32_bf16(
              areg[ch][s], bh, acc[ni], 0, 0, 0);
        }
      }
      // ---- scoring at tile end (barrier-free; R5/R6-proven) ----
      if (ch == 3) {
        const int kc0 = nt * BN;
        #pragma unroll
        for (int r = 0; r < 4; ++r) {
          const int row = wm * 16 + quad * 4 + r;
          const float z2r = z2s[row];
          float dqv[4];
          #pragma unroll
          for (int ni = 0; ni < 4; ++ni)
            dqv[ni] = __fsub_rn(__fadd_rn(z2r, e2all[kc0 + wn * 64 + ni * 16 + lr]),
                                __fmul_rn(2.f, acc[ni][r]));
          float mm = fminf(fminf(dqv[0], dqv[1]), fminf(dqv[2], dqv[3]));
          #pragma unroll
          for (int off = 1; off < 16; off <<= 1)
            mm = fminf(mm, __shfl_xor(mm, off));
          if (lr == 0) atomicMin(&Mlds[row], __float_as_uint(mm));
          float Mst = __uint_as_float(Mlds[row]);  // stale upper bound
          float base = fminf(mm, Mst);
          float thr = fmaf(base, TC_FACT, base);
          #pragma unroll
          for (int ni = 0; ni < 4; ++ni) {
            float dq = dqv[ni];
            int col = kc0 + wn * 64 + ni * 16 + lr;
            // strict < keeps first (smallest col) on ties; cols ascend
            if (dq < v1[r]) { v1[r] = dq; i1f[r] = (float)col; }
            if (dq < thr) {
              unsigned pp = atomicAdd(&cntl[row], 1u);
              if (pp < CAP_BIG) {
                lval[row * CAP_BIG + pp] = dq;
                lidx[row * CAP_BIG + pp] = (u16)col;
              }
            }
            acc[ni][r] = 0.f;   // reset for next tile
          }
        }
      }
    }
  }

  // ---- butterfly top-1 merge over the 16 col lanes (lr) ----
  #pragma unroll
  for (int off = 1; off < 16; off <<= 1) {
    #pragma unroll
    for (int s = 0; s < 4; ++s) {
      float ov1 = __shfl_xor(v1[s], off);
      float oi1 = __shfl_xor(i1f[s], off);
      bool take = (ov1 < v1[s]) || (ov1 == v1[s] && oi1 < i1f[s]);
      if (take) { v1[s] = ov1; i1f[s] = oi1; }
    }
  }
  // ---- per-wave (col-half) results to LDS (alias dead B bufs), merge ----
  __syncthreads();   // real fence+barrier: all compute + appends + DMAs done
  float* mv1 = (float*)Bh4;        // [2][64]
  float* mi1 = mv1 + 2 * BM;
  if (lr == 0) {
    #pragma unroll
    for (int r = 0; r < 4; ++r) {
      int row = wm * 16 + quad * 4 + r;   // 0..63
      mv1[wn * BM + row] = v1[r];
      mi1[wn * BM + row] = i1f[r];
    }
  }
  __syncthreads();
  if (t < BM) {
    float a1 = mv1[t], ai = mi1[t];
    float c1 = mv1[BM + t], ci = mi1[BM + t];
    bool take = (c1 < a1) || (c1 == a1 && ci < ai);
    float b1 = take ? c1 : a1;
    float bi = take ? ci : ai;
    out_idx[row0 + t] = bi;    // provisional winner (fixup overwrites flagged)
    // filter collected candidates against the final row min
    unsigned raw = cntl[t];
    float tf = fmaf(b1, TF_FACT, b1);
    int c = 0;
    u16 keep[CAP];
    bool ovf = raw > (unsigned)CAP_BIG;
    if (!ovf) {
      for (unsigned j = 0; j < raw; ++j) {
        if (lval[t * CAP_BIG + j] <= tf) {
          if (c < CAP) keep[c] = lidx[t * CAP_BIG + j];
          ++c;
        }
      }
      if (c > CAP) ovf = true;
    }
    if (ovf) {
      int o = atomicAdd(&qarr[1], 1);          // OV queue, top-down
      qarr[2 + NN - 1 - o] = row0 + t;
    } else if (c > 1) {
      int q = atomicAdd(&qarr[0], 1);          // list queue, bottom-up
      qarr[2 + q] = (row0 + t) | (c << 16);
      #pragma unroll
      for (int j = 0; j < CAP; ++j)
        cand[(size_t)q * CAP + j] = (j < c) ? keep[j] : (u16)0;
    }
    // ---- loss: sum of winner dq over this block's 64 rows (wave 0 only) ----
    float ls = b1;
    #pragma unroll
    for (int off = 32; off; off >>= 1) ls += __shfl_down(ls, off);
    if (t == 0) atomicAdd(loss_ws, ls);
  }
}

// ---------- fixup: exact f64-rounded f32 dots for listed candidates ----------
__global__ __launch_bounds__(256)
void fixup_k(const float* __restrict__ z, const float* __restrict__ emb,
             const float* __restrict__ e2np, const float* __restrict__ z2np,
             const int* __restrict__ qarr, const u16* __restrict__ cand,
             float* __restrict__ out_idx) {
  int qcnt = qarr[0];
  if (qcnt > NN) qcnt = NN;
  const int t = threadIdx.x;
  const int lane = t & 63, w = t >> 6;
  for (int q = blockIdx.x * 4 + w; q < qcnt; q += gridDim.x * 4) {
    int e = qarr[2 + q];
    int n = e & 0xffff;
    int c = e >> 16;
    int b = n >> 12, s = n & (SS - 1);
    float z2 = z2np[n];
    const float* zb = z + (((size_t)b * C) << 12) + s;
    float4 zv;
    zv.x = zb[((size_t)(lane * 4 + 0)) << 12];
    zv.y = zb[((size_t)(lane * 4 + 1)) << 12];
    zv.z = zb[((size_t)(lane * 4 + 2)) << 12];
    zv.w = zb[((size_t)(lane * 4 + 3)) << 12];
    float bestd = 3.4e38f;
    int besti = 0x7fffffff;
    for (int j = 0; j < c; ++j) {
      int kk = (int)cand[(size_t)q * CAP + j];
      const float4 ev = *(const float4*)&emb[(size_t)kk * C + lane * 4];
      double acc = (double)zv.x * (double)ev.x;
      acc = fma((double)zv.y, (double)ev.y, acc);
      acc = fma((double)zv.z, (double)ev.z, acc);
      acc = fma((double)zv.w, (double)ev.w, acc);
      #pragma unroll
      for (int off = 32; off; off >>= 1) acc += __shfl_xor(acc, off);
      float g  = (float)acc;           // correctly-rounded f32 dot
      float t1 = __fadd_rn(z2, e2np[kk]);
      float d  = __fsub_rn(t1, __fmul_rn(2.f, g));
      if (d < bestd || (d == bestd && kk < besti)) { bestd = d; besti = kk; }
    }
    if (lane == 0) out_idx[n] = (float)besti;
  }
}

// ---------- fixov: block-parallel exact full scan for OV rows ----------
__global__ __launch_bounds__(256)
void fixov_k(const float* __restrict__ z, const float* __restrict__ emb,
             const float* __restrict__ e2np, const float* __restrict__ z2np,
             const int* __restrict__ qarr, float* __restrict__ out_idx) {
  __shared__ float zrow[C];
  __shared__ float bv[4];
  __shared__ int   bx[4];
  int novr = qarr[1];
  if (novr > NN) novr = NN;
  const int t = threadIdx.x;
  const int lane = t & 63, w = t >> 6;
  for (int o = blockIdx.x; o < novr; o += gridDim.x) {
    int n = qarr[2 + NN - 1 - o];
    int b = n >> 12, s = n & (SS - 1);
    __syncthreads();   // prior iter's zrow readers done
    zrow[t] = z[((size_t)(b * C + t) << 12) + s];
    __syncthreads();
    float z2 = z2np[n];
    float best = 3.4e38f; int besti = 0x7fffffff;
    for (int kk = t; kk < K; kk += 256) {
      const float* er = emb + (size_t)kk * C;
      double a0 = 0.0, a1 = 0.0, a2 = 0.0, a3 = 0.0;
      for (int c = 0; c < C; c += 4) {
        a0 = fma((double)zrow[c + 0], (double)er[c + 0], a0);
        a1 = fma((double)zrow[c + 1], (double)er[c + 1], a1);
        a2 = fma((double)zrow[c + 2], (double)er[c + 2], a2);
        a3 = fma((double)zrow[c + 3], (double)er[c + 3], a3);
      }
      float g = (float)((a0 + a1) + (a2 + a3));
      float t1 = __fadd_rn(z2, e2np[kk]);
      float d  = __fsub_rn(t1, __fmul_rn(2.f, g));
      if (d < best || (d == best && kk < besti)) { best = d; besti = kk; }
    }
    #pragma unroll
    for (int off = 32; off; off >>= 1) {
      float ov = __shfl_down(best, off);
      int   oi = __shfl_down(besti, off);
      if (ov < best || (ov == best && oi < besti)) { best = ov; besti = oi; }
    }
    if (lane == 0) { bv[w] = best; bx[w] = besti; }
    __syncthreads();
    if (t == 0) {
      #pragma unroll
      for (int w2 = 1; w2 < 4; ++w2)
        if (bv[w2] < best || (bv[w2] == best && bx[w2] < besti)) {
          best = bv[w2]; besti = bx[w2];
        }
      out_idx[n] = (float)besti;
    }
  }
}

// ---------- gather: LDS-staged emb rows -> vectorized zq write + histogram ----------
// R10: z is no longer read here (loss comes from vq's winner-dq sum);
// out writes are float4 along s (4x fewer store instrs, 1 KB/wave-op).
#define GROWS 64
__global__ __launch_bounds__(256)
void gather2_k(const float* __restrict__ emb, float* __restrict__ out,
               float* __restrict__ counts) {
  __shared__ float eb[GROWS * 257];
  __shared__ int idxs[GROWS];
  const int t = threadIdx.x;
  const int n0 = blockIdx.x * GROWS;
  const int b = n0 >> 12;
  const int s0 = n0 & (SS - 1);
  if (t < GROWS) {
    int id = (int)out[OUT_IDX + n0 + t];
    idxs[t] = id;
    atomicAdd(&counts[id], 1.0f);
  }
  __syncthreads();
  #pragma unroll
  for (int i = 0; i < 16; ++i) {
    int q = i * 256 + t;
    int row = q >> 6, c4 = q & 63;
    float4 v = *(const float4*)&emb[(size_t)idxs[row] * C + c4 * 4];
    int base = row * 257 + c4 * 4;
    eb[base + 0] = v.x; eb[base + 1] = v.y;
    eb[base + 2] = v.z; eb[base + 3] = v.w;
  }
  __syncthreads();
  const int sl4 = t & 15, cg = t >> 4;
  float* ob = out + (size_t)b * C * SS + s0 + sl4 * 4;
  #pragma unroll
  for (int i = 0; i < 16; ++i) {
    int c = cg * 16 + i;
    int base = (sl4 * 4) * 257 + c;
    float4 v;
    v.x = eb[base];
    v.y = eb[base + 257];
    v.z = eb[base + 2 * 257];
    v.w = eb[base + 3 * 257];
    *(float4*)&ob[(size_t)c * SS] = v;
  }
}

// ---------- finalize scalars ----------
__global__ void finalize_k(const float* __restrict__ ws, float* __restrict__ out) {
  __shared__ float sc[8];
  int t = threadIdx.x;
  float ent = 0.f;
  #pragma unroll
  for (int k = t; k < K; k += 256) {
    float em = ws[WS_CNT + k] * (1.0f / NN);
    ent += em * logf(em + 1e-10f);
  }
  float zd = ws[WS_ZSUM + t] * ws[WS_ESUM + t];
  #pragma unroll
  for (int off = 32; off; off >>= 1) {
    ent += __shfl_down(ent, off);
    zd  += __shfl_down(zd, off);
  }
  int lane = t & 63, w = t >> 6;
  if (lane == 0) { sc[w] = ent; sc[4 + w] = zd; }
  __syncthreads();
  if (t == 0) {
    ent = sc[0] + sc[1] + sc[2] + sc[3];
    zd  = sc[4] + sc[5] + sc[6] + sc[7];
    out[OUT_LOSS] = 1.25f * ws[WS_LOSS] * (1.0f / ZQ_ELEMS);
    out[OUT_PERP] = expf(-ent);
    out[OUT_MD]   = ws[WS_SZ2] * (1.0f / NN) + ws[WS_SE2] * (1.0f / K)
                  - 2.0f * zd * (1.0f / ((float)NN * (float)K));
  }
}

extern "C" void kernel_launch(void* const* d_in, const int* in_sizes, int n_in,
                              void* d_out, int out_size, void* d_ws, size_t ws_size,
                              hipStream_t stream) {
  const float* z   = (const float*)d_in[0];
  const float* emb = (const float*)d_in[1];
  float* out = (float*)d_out;
  float* ws  = (float*)d_ws;
  int* qarr = (int*)(ws + WS_FLG);
  u16* cand = (u16*)(ws + WS_CAND);
  u16* eh_g = (u16*)(ws + WS_EH);
  // zh lives in d_out's zq region; overwritten by gather2_k at the end.
  u16* zh_g = (u16*)d_out;
  (void)in_sizes; (void)n_in; (void)out_size; (void)ws_size;

  hipMemsetAsync(d_ws, 0, WS_E2R * sizeof(float), stream);
  hipMemsetAsync(ws + WS_FLG, 0, 2 * sizeof(int), stream);
  emb_prep_k<<<64, 256, 0, stream>>>(emb, ws, eh_g);
  prep_z_k<<<NN / MROWS, 256, 0, stream>>>(z, ws, zh_g);
  size_t lds = (size_t)(4 * BN * CH) * sizeof(u16)
             + (size_t)(K + BM + BM * CAP_BIG) * sizeof(float)
             + (size_t)(2 * BM) * sizeof(unsigned)
             + (size_t)(BM * CAP_BIG) * sizeof(u16);
  vq_mfma_k<<<NN / BM, 512, lds, stream>>>(zh_g, eh_g,
                                           ws + WS_E2R, ws + WS_Z2N,
                                           out + OUT_IDX, qarr, cand,
                                           ws + WS_LOSS);
  fixup_k<<<512, 256, 0, stream>>>(z, emb, ws + WS_E2R, ws + WS_Z2N,
                                   qarr, cand, out + OUT_IDX);
  fixov_k<<<512, 256, 0, stream>>>(z, emb, ws + WS_E2R, ws + WS_Z2N,
                                   qarr, out + OUT_IDX);
  gather2_k<<<NN / GROWS, 256, 0, stream>>>(emb, out, ws + WS_CNT);
  finalize_k<<<1, 256, 0, stream>>>(ws, out);
}